// Round 15
// baseline (95.621 us; speedup 1.0000x reference)
//
#include <hip/hip_runtime.h>

// BPS pipeline v15: FULLY FUSED single kernel. 512 blocks x 512 threads,
// 128 outputs/block (257-row tile, halo 65 left / 64 right). Each block:
//   dist -> P1 prefix -> box65 diff -> Q prefix -> mvg diff -> softmin -> ang[129] in LDS
//   -> local unwrap-correction scan -> decoupled lookback (flags self-init: poison!=1)
//   -> ph & rotated output written directly.
// Boundary ang[l0-1] recomputed redundantly per block (threshold decision robust:
// wraps have |dd|~2pi, non-wraps ~0; both far from the pi threshold).
// d_out = f32[2L]: [0,L) = real(x*exp(i*ph)), [L,2L) = ph = unwrap(ang)/4.

#define LN   65536
#define PI_F 3.14159265358979323846f
#define TWO_PI_F 6.2831853071795864769f

#define CORR(dd) (((dd) < -PI_F) ? 1 : (((dd) > PI_F) ? -1 : 0))

__global__ __launch_bounds__(512) void v15_fused(const float* __restrict__ xr,
                                                 const float* __restrict__ xi,
                                                 const float* __restrict__ temp,
                                                 int* __restrict__ partial,
                                                 int* __restrict__ flags,
                                                 float* __restrict__ out_base) {
    __shared__ float P1[64 * 258];       // P1[m][li], li=0..256; reused as Q[m*195+j]
    __shared__ float xsr[260], xsi[260]; // staged x tile rows l0-65 .. l0+191
    __shared__ float tot1[8][64];
    __shared__ float tot2[8][64];
    __shared__ float s4v[64], c4v[64];
    __shared__ float ang_lds[129];       // ang[l0-1 .. l0+127]
    __shared__ int   wtot[2];
    __shared__ int   s_boff;

    const int t   = threadIdx.x;
    const int b   = blockIdx.x;
    const int l0  = b * 128;
    const int m   = t & 63;
    const int seg = t >> 6;              // wave id

    if (t < 257) {
        int gl = l0 - 65 + t;
        bool ok = (unsigned)gl < (unsigned)LN;
        xsr[t] = ok ? xr[gl] : 0.0f;
        xsi[t] = ok ? xi[gl] : 0.0f;
    }
    if (t >= 448) {                      // separate wave fills trig table
        int mm = t - 448;
        float a4 = (float)mm * (PI_F / 32.0f) - PI_F;   // 4*angles[mm]
        float s, c; sincosf(a4, &s, &c);
        s4v[mm] = s; c4v[mm] = c;
    }
    __syncthreads();

    // ---- Phase 1: dist (separable nearest-64QAM quantization) + register prefix.
    //      seg owns rows li = seg*33 .. seg*33+32 (last seg: 26 rows). ----
    {
        const float am = (float)m * (PI_F / 128.0f) - (PI_F * 0.25f);
        float sm, cm; sincosf(am, &sm, &cm);
        const float SQ = 6.4807406984078602f;   // sqrt(42)
        const float cq = cm * SQ, sq = sm * SQ;
        const int li0 = seg * 33;
        const int rn  = (seg < 7) ? 33 : 26;    // 7*33 + 26 = 257
        float pr[33];
        float p = 0.0f;
        #pragma unroll
        for (int i = 0; i < 33; ++i) {
            if (i < rn) {
                int li = li0 + i;
                float a = xsr[li], bb = xsi[li];   // LDS b32 broadcast
                float tr = a * cq - bb * sq;
                float ti = a * sq + bb * cq;
                float rr = fminf(fmaxf(rintf(fmaf(tr, 0.5f, 3.5f)), 0.0f), 7.0f);
                float ri = fminf(fmaxf(rintf(fmaf(ti, 0.5f, 3.5f)), 0.0f), 7.0f);
                float dr = fmaf(-2.0f, rr, tr + 7.0f);
                float di = fmaf(-2.0f, ri, ti + 7.0f);
                float d = fmaf(dr, dr, di * di) * (1.0f / 42.0f);
                d = ((unsigned)(l0 - 65 + li) < (unsigned)LN) ? d : 0.0f;  // conv zero-pad
                p += d;
                pr[i] = p;
            }
        }
        tot1[seg][m] = p;
        __syncthreads();
        float off = 0.0f;
        #pragma unroll
        for (int s = 0; s < 7; ++s) if (s < seg) off += tot1[s][m];
        #pragma unroll
        for (int i = 0; i < 33; ++i) if (i < rn) P1[m * 258 + li0 + i] = pr[i] + off;
    }
    __syncthreads();

    // ---- Phase 2: box1[j] = P1[j+64] - P1[j-1] (65-wide box sums), j=0..192;
    //      register prefix -> Q[m][j] (reuses P1 storage after barrier). ----
    {
        const int j0 = seg * 25;
        const int jn = (j0 < 193) ? ((193 - j0 < 25) ? (193 - j0) : 25) : 0;  // seg7: 18
        float q[25];
        float p2 = 0.0f;
        #pragma unroll
        for (int i = 0; i < 25; ++i) {
            if (i < jn) {
                int j = j0 + i;
                float hi = P1[m * 258 + j + 64];
                float lo = (j >= 1) ? P1[m * 258 + j - 1] : 0.0f;
                p2 += hi - lo;
                q[i] = p2;
            }
        }
        tot2[seg][m] = p2;
        __syncthreads();                     // all P1 reads done; reuse storage as Q
        float off2 = 0.0f;
        #pragma unroll
        for (int s = 0; s < 7; ++s) if (s < seg) off2 += tot2[s][m];
        float* Q = P1;                       // Q[m][j] at m*195 + j
        #pragma unroll
        for (int i = 0; i < 25; ++i) if (i < jn) Q[m * 195 + j0 + i] = q[i] + off2;
    }
    __syncthreads();

    // ---- Phase 3: mvg[rr][mm] = Q[mm][rr+64] - (rr>=1 ? Q[mm][rr-1] : 0), rr=0..128
    //      (ang[l0-1+rr]); softmin+atan2, 4 lanes/row; pass B covers rr=128. ----
    {
        const float* Q = P1;
        const float T = temp[0];
        #pragma unroll
        for (int pass = 0; pass < 2; ++pass) {
            int rr;
            bool act;
            if (pass == 0) { rr = t >> 2; act = true; }       // rr = 0..127
            else           { rr = 128;    act = (t < 4); }    // rr = 128
            if (act) {
                const int sub = t & 3;
                const int mb  = sub * 16;
                float v[16];
                float rs = 0.0f, mn = 3.4e38f;
                #pragma unroll
                for (int i = 0; i < 16; ++i) {
                    int mm = mb + i;
                    float hi = Q[mm * 195 + rr + 64];
                    float lo = (rr >= 1) ? Q[mm * 195 + rr - 1] : 0.0f;
                    float vv = hi - lo;
                    v[i] = vv; rs += vv; mn = fminf(mn, vv);
                }
                rs += __shfl_xor(rs, 1, 64); rs += __shfl_xor(rs, 2, 64);
                mn = fminf(mn, __shfl_xor(mn, 1, 64)); mn = fminf(mn, __shfl_xor(mn, 2, 64));
                float inv = 1.0f / (rs * T);
                float ss = 0.0f, sc = 0.0f;
                #pragma unroll
                for (int i = 0; i < 16; ++i) {
                    int mm = mb + i;
                    float e = __expf((mn - v[i]) * inv);
                    ss = fmaf(e, s4v[mm], ss);
                    sc = fmaf(e, c4v[mm], sc);
                }
                ss += __shfl_xor(ss, 1, 64); ss += __shfl_xor(ss, 2, 64);
                sc += __shfl_xor(sc, 1, 64); sc += __shfl_xor(sc, 2, 64);
                if ((t & 3) == 0) ang_lds[rr] = atan2f(ss, sc);
            }
        }
    }
    __syncthreads();

    // ---- Phase 4: local correction scan (t<128, 2 waves), publish + lookback ----
    int incl = 0, c = 0;
    if (t < 128) {
        // correction for element l = l0 + t: prev = ang_lds[t], cur = ang_lds[t+1]
        float dd = ang_lds[t + 1] - ang_lds[t];
        c = CORR(dd);
        if (b == 0 && t == 0) c = 0;      // np.unwrap: first element unchanged
        const int lane = t & 63, w = t >> 6;
        int sc = c;
        #pragma unroll
        for (int off = 1; off < 64; off <<= 1) {
            int v = __shfl_up(sc, off, 64);
            if (lane >= off) sc += v;
        }
        if (lane == 63) wtot[w] = sc;
        incl = sc;
    }
    __syncthreads();
    if (t < 128) {
        if ((t >> 6) == 1) incl += wtot[0];
    }
    if (t == 0) {
        int btot = wtot[0] + wtot[1];
        __hip_atomic_store(&partial[b], btot, __ATOMIC_RELAXED, __HIP_MEMORY_SCOPE_AGENT);
        __hip_atomic_store(&flags[b], 1, __ATOMIC_RELEASE, __HIP_MEMORY_SCOPE_AGENT);
    }
    if (t < 64) {
        int v = 0;
        for (int p = t; p < b; p += 64) {
            while (__hip_atomic_load(&flags[p], __ATOMIC_ACQUIRE, __HIP_MEMORY_SCOPE_AGENT) != 1) {}
            v += __hip_atomic_load(&partial[p], __ATOMIC_RELAXED, __HIP_MEMORY_SCOPE_AGENT);
        }
        #pragma unroll
        for (int off = 1; off < 64; off <<= 1) v += __shfl_xor(v, off, 64);
        if (t == 0) s_boff = v;
    }
    __syncthreads();

    // ---- Phase 5: apply ph & rotate, direct output (t<128; coalesced) ----
    if (t < 128) {
        const int l = l0 + t;
        int k = s_boff + incl;
        float ph = (ang_lds[t + 1] + TWO_PI_F * (float)k) * 0.25f;
        float s, cc; sincosf(ph, &s, &cc);
        float a = xr[l], bb = xi[l];
        out_base[l]      = a * cc - bb * s;   // real(out)
        out_base[LN + l] = ph;                // ph channel
    }
}

extern "C" void kernel_launch(void* const* d_in, const int* in_sizes, int n_in,
                              void* d_out, int out_size, void* d_ws, size_t ws_size,
                              hipStream_t stream) {
    (void)in_sizes; (void)n_in; (void)out_size; (void)ws_size;
    const float* xr   = (const float*)d_in[0];
    const float* xi   = (const float*)d_in[1];
    const float* temp = (const float*)d_in[5];

    int* partial = (int*)d_ws;                    // 512 i32
    int* flags   = (int*)((char*)d_ws + 4096);    // 512 i32 (poison 0xAA != 1 -> self-init)

    v15_fused<<<512, 512, 0, stream>>>(xr, xi, temp, partial, flags, (float*)d_out);
}